// Round 4
// baseline (2301.752 us; speedup 1.0000x reference)
//
#include <hip/hip_runtime.h>

#define BN 128
#define DTCF 512
#define TT 1024
#define GAF 256
#define DKK 32
#define HID 64
#define NCLS 4
#define LNEPS 1e-5f
#define DC 8          // d-chunks in pass A
#define DCL (DTCF/DC) // 64 d per chunk
#define NBLK_B (DTCF/4) // passB blocks per b = 128

// ---------------------------------------------------------------------------
// Kernel 1: pass A over tcf, with per-block KV/u/qv precompute fused in.
//   KV[k] = sum_g gaf[b,g]*Wkv[k,g]; u_d = sum_k KV*Wout[d,k]; qv_d = KV.Wq[:,d]
// Grid (BN, DC). Block covers all T; thread owns 4 consecutive t (float4).
// Emits per-(b,chunk,t) partials {sx,sxx,sxu,sxq} and u[b,chunk].
// ---------------------------------------------------------------------------
__global__ __launch_bounds__(256) void k_passA(
    const float* __restrict__ tcf, const float* __restrict__ gaf,
    const float* __restrict__ Wq, const float* __restrict__ Wkv,
    const float* __restrict__ Wout,
    float* __restrict__ u_g, float* __restrict__ part)
{
    int b = blockIdx.x, dc = blockIdx.y, tid = threadIdx.x;
    __shared__ float gaf_s[GAF];
    __shared__ float kvp[DKK][9];
    __shared__ float kv_s[DKK];
    __shared__ float u_s[DCL], qv_s[DCL];

    gaf_s[tid] = gaf[b * GAF + tid];          // blockDim == GAF == 256
    __syncthreads();
    {   // KV: 8 threads per k
        int k = tid >> 3, p8 = tid & 7;
        float acc = 0.f;
        #pragma unroll
        for (int g = p8 * 32; g < p8 * 32 + 32; ++g)
            acc += gaf_s[g] * Wkv[k * GAF + g];
        kvp[k][p8] = acc;
    }
    __syncthreads();
    if (tid < DKK) {
        float a = 0.f;
        #pragma unroll
        for (int p = 0; p < 8; ++p) a += kvp[tid][p];
        kv_s[tid] = a;
    }
    __syncthreads();
    if (tid < DCL) {
        int d = dc * DCL + tid;
        float uu = 0.f, qq = 0.f;
        #pragma unroll
        for (int k = 0; k < DKK; ++k) {
            float kv = kv_s[k];
            uu += kv * Wout[d * DKK + k];
            qq += kv * Wq[k * DTCF + d];
        }
        u_s[tid] = uu; qv_s[tid] = qq;
        u_g[b * DTCF + d] = uu;
    }
    __syncthreads();

    int t0 = tid * 4;
    const float* base = tcf + ((size_t)b * DTCF + dc * DCL) * TT + t0;
    float4 sx = {0,0,0,0}, sxx = {0,0,0,0}, sxu = {0,0,0,0}, sxq = {0,0,0,0};
    #pragma unroll 4
    for (int d = 0; d < DCL; ++d) {
        float4 v = *(const float4*)(base + (size_t)d * TT);
        float uu = u_s[d], qq = qv_s[d];
        sx.x += v.x; sx.y += v.y; sx.z += v.z; sx.w += v.w;
        sxx.x += v.x*v.x; sxx.y += v.y*v.y; sxx.z += v.z*v.z; sxx.w += v.w*v.w;
        sxu.x += v.x*uu; sxu.y += v.y*uu; sxu.z += v.z*uu; sxu.w += v.w*uu;
        sxq.x += v.x*qq; sxq.y += v.y*qq; sxq.z += v.z*qq; sxq.w += v.w*qq;
    }
    float* p = part + (((size_t)b * DC + dc) * 4) * TT + t0;
    *(float4*)(p)          = sx;
    *(float4*)(p + TT)     = sxx;
    *(float4*)(p + 2 * TT) = sxu;
    *(float4*)(p + 3 * TT) = sxq;
}

// ---------------------------------------------------------------------------
// Kernel 2: per-b: muu/varu from u, combine partials, softmax over T,
// r_t = rsqrt(var_t+eps), S2 = mean r*w, S3 = mean r*mx. Zeroes cnt[b].
// ---------------------------------------------------------------------------
__global__ __launch_bounds__(256) void k_soft(
    const float* __restrict__ part, const float* __restrict__ u_g,
    float* __restrict__ r_o, float* __restrict__ S2, float* __restrict__ S3,
    float* __restrict__ muu_g, int* __restrict__ cnt)
{
    int b = blockIdx.x, tid = threadIdx.x;
    int lane = tid & 63, wv = tid >> 6;
    __shared__ float red[16];
    __shared__ float stat[2];   // muu, varu
    if (tid == 0) cnt[b] = 0;

    // muu / varu
    float su = 0.f, suu = 0.f;
    for (int d = tid; d < DTCF; d += 256) {
        float x = u_g[b * DTCF + d];
        su += x; suu += x * x;
    }
    for (int off = 32; off > 0; off >>= 1) {
        su  += __shfl_xor(su, off);
        suu += __shfl_xor(suu, off);
    }
    if (lane == 0) { red[wv] = su; red[8 + wv] = suu; }
    __syncthreads();
    if (tid == 0) {
        float s  = red[0] + red[1] + red[2] + red[3];
        float ss = red[8] + red[9] + red[10] + red[11];
        float m = s * (1.f / DTCF);
        stat[0] = m;
        stat[1] = ss * (1.f / DTCF) - m * m;
        muu_g[b] = m;
    }
    __syncthreads();
    float mu = stat[0], vu = stat[1];

    int t0 = tid * 4;
    float4 sx = {0,0,0,0}, sxx = {0,0,0,0}, sxu = {0,0,0,0}, sxq = {0,0,0,0};
    #pragma unroll
    for (int dc = 0; dc < DC; ++dc) {
        const float* p = part + (((size_t)b * DC + dc) * 4) * TT + t0;
        float4 a = *(const float4*)(p);
        float4 bq = *(const float4*)(p + TT);
        float4 c = *(const float4*)(p + 2 * TT);
        float4 dq = *(const float4*)(p + 3 * TT);
        sx.x += a.x; sx.y += a.y; sx.z += a.z; sx.w += a.w;
        sxx.x += bq.x; sxx.y += bq.y; sxx.z += bq.z; sxx.w += bq.w;
        sxu.x += c.x; sxu.y += c.y; sxu.z += c.z; sxu.w += c.w;
        sxq.x += dq.x; sxq.y += dq.y; sxq.z += dq.z; sxq.w += dq.w;
    }
    const float inv_d = 1.f / DTCF, scale = 0.17677669529663687f;
    float mx[4], vx[4], cv[4], sc[4];
    float sxa[4]  = {sx.x, sx.y, sx.z, sx.w};
    float sxxa[4] = {sxx.x, sxx.y, sxx.z, sxx.w};
    float sxua[4] = {sxu.x, sxu.y, sxu.z, sxu.w};
    float sxqa[4] = {sxq.x, sxq.y, sxq.z, sxq.w};
    #pragma unroll
    for (int i = 0; i < 4; ++i) {
        mx[i] = sxa[i] * inv_d;
        vx[i] = sxxa[i] * inv_d - mx[i] * mx[i];
        cv[i] = sxua[i] * inv_d - mx[i] * mu;
        sc[i] = sxqa[i] * scale;
    }

    float m = fmaxf(fmaxf(sc[0], sc[1]), fmaxf(sc[2], sc[3]));
    for (int off = 32; off > 0; off >>= 1) m = fmaxf(m, __shfl_xor(m, off));
    if (lane == 0) red[wv] = m;
    __syncthreads();
    m = fmaxf(fmaxf(red[0], red[1]), fmaxf(red[2], red[3]));

    float e[4], sum = 0.f;
    #pragma unroll
    for (int i = 0; i < 4; ++i) { e[i] = __expf(sc[i] - m); sum += e[i]; }
    for (int off = 32; off > 0; off >>= 1) sum += __shfl_xor(sum, off);
    if (lane == 0) red[4 + wv] = sum;
    __syncthreads();
    sum = red[4] + red[5] + red[6] + red[7];
    float inv = 1.f / sum;

    float rr4[4], s2a = 0.f, s3a = 0.f;
    #pragma unroll
    for (int i = 0; i < 4; ++i) {
        float w = e[i] * inv;
        float vr = vx[i] + 2.f * w * cv[i] + w * w * vu;
        float rr = rsqrtf(vr + LNEPS);
        rr4[i] = rr;
        s2a += rr * w;
        s3a += rr * mx[i];
    }
    *(float4*)(r_o + (size_t)b * TT + t0) = make_float4(rr4[0], rr4[1], rr4[2], rr4[3]);

    for (int off = 32; off > 0; off >>= 1) {
        s2a += __shfl_xor(s2a, off);
        s3a += __shfl_xor(s3a, off);
    }
    if (lane == 0) { red[8 + wv] = s2a; red[12 + wv] = s3a; }
    __syncthreads();
    if (tid == 0) {
        S2[b] = (red[8] + red[9] + red[10] + red[11]) * (1.f / TT);
        S3[b] = (red[12] + red[13] + red[14] + red[15]) * (1.f / TT);
    }
}

// ---------------------------------------------------------------------------
// Kernel 3: pass B + fused head. One wave per (b,d) row: dot(r, tcf row).
// Reverse-b mapping for L3 residue. Last block per b (threadfence-reduction
// idiom) computes the MLP head for that b and writes the 4 outputs.
// ---------------------------------------------------------------------------
__global__ __launch_bounds__(256) void k_passB(
    const float* __restrict__ tcf, const float* __restrict__ r,
    const float* __restrict__ u_g, const float* __restrict__ muu_g,
    const float* __restrict__ S2, const float* __restrict__ S3,
    const float* __restrict__ g1, const float* __restrict__ be1,
    const float* __restrict__ W1, const float* __restrict__ b1,
    const float* __restrict__ g2, const float* __restrict__ be2,
    const float* __restrict__ W2, const float* __restrict__ b2o,
    float* __restrict__ pooled, int* __restrict__ cnt,
    float* __restrict__ out)
{
    int b = BN - 1 - blockIdx.x, dblk = blockIdx.y;
    int tid = threadIdx.x, wv = tid >> 6, lane = tid & 63;
    int d = dblk * 4 + wv;

    const float* row = tcf + ((size_t)b * DTCF + d) * TT;
    const float* rb  = r + (size_t)b * TT;

    float acc = 0.f;
    #pragma unroll
    for (int i = 0; i < 4; ++i) {
        float4 x  = *(const float4*)(row + i * 256 + lane * 4);
        float4 rv = *(const float4*)(rb + i * 256 + lane * 4);
        acc += rv.x * x.x + rv.y * x.y + rv.z * x.z + rv.w * x.w;
    }
    for (int off = 32; off > 0; off >>= 1) acc += __shfl_down(acc, off);

    if (lane == 0) {
        float pd = acc * (1.f / TT) - S3[b] + (u_g[b * DTCF + d] - muu_g[b]) * S2[b];
        pooled[b * DTCF + d] = g1[d] * pd + be1[d];
        __threadfence();   // release this wave's pooled write to device scope
    }
    __syncthreads();

    __shared__ int is_last;
    if (tid == 0) is_last = (atomicAdd(&cnt[b], 1) == NBLK_B - 1);
    __syncthreads();
    if (!is_last) return;
    __threadfence();       // acquire: see all other blocks' pooled writes

    // ---- fused head for batch b ----
    __shared__ float p_s[DTCF];
    __shared__ float h_s[HID];
    for (int i = tid; i < DTCF; i += 256) p_s[i] = pooled[b * DTCF + i];
    __syncthreads();

    // 64 rows of W1 (length 512): wave wv handles j = wv*16..+15, coalesced.
    #pragma unroll 4
    for (int jj = 0; jj < 16; ++jj) {
        int j = wv * 16 + jj;
        float a = 0.f;
        #pragma unroll
        for (int i = 0; i < 8; ++i)
            a += p_s[i * 64 + lane] * W1[j * DTCF + i * 64 + lane];
        for (int off = 32; off > 0; off >>= 1) a += __shfl_down(a, off);
        if (lane == 0) h_s[j] = a + b1[j];
    }
    __syncthreads();

    if (wv == 0) {
        int j = lane;
        float h = h_s[j];
        float mu = h;
        for (int off = 32; off > 0; off >>= 1) mu += __shfl_xor(mu, off);
        mu *= (1.f / HID);
        float df = h - mu;
        float vr = df * df;
        for (int off = 32; off > 0; off >>= 1) vr += __shfl_xor(vr, off);
        vr *= (1.f / HID);
        float hn = df * rsqrtf(vr + LNEPS) * g2[j] + be2[j];
        float he = hn > 0.f ? hn : expm1f(hn);
        #pragma unroll
        for (int c = 0; c < NCLS; ++c) {
            float v = he * W2[c * HID + j];
            for (int off = 32; off > 0; off >>= 1) v += __shfl_xor(v, off);
            if (j == 0) out[b * NCLS + c] = v + b2o[c];
        }
    }
}

extern "C" void kernel_launch(void* const* d_in, const int* in_sizes, int n_in,
                              void* d_out, int out_size, void* d_ws, size_t ws_size,
                              hipStream_t stream)
{
    const float* tcf  = (const float*)d_in[0];
    const float* gaf  = (const float*)d_in[1];
    const float* Wq   = (const float*)d_in[2];
    const float* Wkv  = (const float*)d_in[3];
    const float* Wout = (const float*)d_in[4];
    const float* ln1g = (const float*)d_in[5];
    const float* ln1b = (const float*)d_in[6];
    const float* W1   = (const float*)d_in[7];
    const float* b1   = (const float*)d_in[8];
    const float* ln2g = (const float*)d_in[9];
    const float* ln2b = (const float*)d_in[10];
    const float* W2   = (const float*)d_in[11];
    const float* b2   = (const float*)d_in[12];

    float* ws     = (float*)d_ws;
    float* u      = ws;                   // B*DTCF
    float* muu    = u + BN * DTCF;        // B
    float* r      = muu + BN;             // B*T
    float* S2     = r + BN * TT;          // B
    float* S3     = S2 + BN;              // B
    float* pooled = S3 + BN;              // B*DTCF
    int*   cnt    = (int*)(pooled + BN * DTCF);   // B
    float* part   = (float*)(cnt + BN) + 32;      // B*DC*4*T

    k_passA<<<dim3(BN, DC), 256, 0, stream>>>(tcf, gaf, Wq, Wkv, Wout, u, part);
    k_soft<<<BN, 256, 0, stream>>>(part, u, r, S2, S3, muu, cnt);
    k_passB<<<dim3(BN, DTCF / 4), 256, 0, stream>>>(
        tcf, r, u, muu, S2, S3, ln1g, ln1b, W1, b1, ln2g, ln2b, W2, b2,
        pooled, cnt, (float*)d_out);
}

// Round 5
// 445.606 us; speedup vs baseline: 5.1654x; 5.1654x over previous
//
#include <hip/hip_runtime.h>

#define BN 128
#define DTCF 512
#define TT 1024
#define GAF 256
#define DKK 32
#define HID 64
#define NCLS 4
#define LNEPS 1e-5f
#define DC 8          // d-chunks in pass A
#define DCL (DTCF/DC) // 64 d per chunk

// ---------------------------------------------------------------------------
// Kernel 1: pass A over tcf, per-block KV/u/qv precompute fused in.
// Grid (BN, DC); thread owns 4 consecutive t (float4 loads).
// Emits per-(b,chunk,t) partials {sx,sxx,sxu,sxq} and u[b,chunk].
// ---------------------------------------------------------------------------
__global__ __launch_bounds__(256) void k_passA(
    const float* __restrict__ tcf, const float* __restrict__ gaf,
    const float* __restrict__ Wq, const float* __restrict__ Wkv,
    const float* __restrict__ Wout,
    float* __restrict__ u_g, float* __restrict__ part)
{
    int b = blockIdx.x, dc = blockIdx.y, tid = threadIdx.x;
    __shared__ float gaf_s[GAF];
    __shared__ float kvp[DKK][9];
    __shared__ float kv_s[DKK];
    __shared__ float u_s[DCL], qv_s[DCL];

    gaf_s[tid] = gaf[b * GAF + tid];          // blockDim == GAF == 256
    __syncthreads();
    {   // KV: 8 threads per k
        int k = tid >> 3, p8 = tid & 7;
        float acc = 0.f;
        #pragma unroll
        for (int g = p8 * 32; g < p8 * 32 + 32; ++g)
            acc += gaf_s[g] * Wkv[k * GAF + g];
        kvp[k][p8] = acc;
    }
    __syncthreads();
    if (tid < DKK) {
        float a = 0.f;
        #pragma unroll
        for (int p = 0; p < 8; ++p) a += kvp[tid][p];
        kv_s[tid] = a;
    }
    __syncthreads();
    if (tid < DCL) {
        int d = dc * DCL + tid;
        float uu = 0.f, qq = 0.f;
        #pragma unroll
        for (int k = 0; k < DKK; ++k) {
            float kv = kv_s[k];
            uu += kv * Wout[d * DKK + k];
            qq += kv * Wq[k * DTCF + d];
        }
        u_s[tid] = uu; qv_s[tid] = qq;
        u_g[b * DTCF + d] = uu;
    }
    __syncthreads();

    int t0 = tid * 4;
    const float* base = tcf + ((size_t)b * DTCF + dc * DCL) * TT + t0;
    float4 sx = {0,0,0,0}, sxx = {0,0,0,0}, sxu = {0,0,0,0}, sxq = {0,0,0,0};
    #pragma unroll 8
    for (int d = 0; d < DCL; ++d) {
        float4 v = *(const float4*)(base + (size_t)d * TT);
        float uu = u_s[d], qq = qv_s[d];
        sx.x += v.x; sx.y += v.y; sx.z += v.z; sx.w += v.w;
        sxx.x += v.x*v.x; sxx.y += v.y*v.y; sxx.z += v.z*v.z; sxx.w += v.w*v.w;
        sxu.x += v.x*uu; sxu.y += v.y*uu; sxu.z += v.z*uu; sxu.w += v.w*uu;
        sxq.x += v.x*qq; sxq.y += v.y*qq; sxq.z += v.z*qq; sxq.w += v.w*qq;
    }
    float* p = part + (((size_t)b * DC + dc) * 4) * TT + t0;
    *(float4*)(p)          = sx;
    *(float4*)(p + TT)     = sxx;
    *(float4*)(p + 2 * TT) = sxu;
    *(float4*)(p + 3 * TT) = sxq;
}

// ---------------------------------------------------------------------------
// Kernel 2: per-b: muu/varu from u, combine partials, softmax over T,
// r_t = rsqrt(var_t+eps), S2 = mean r*w, S3 = mean r*mx.
// ---------------------------------------------------------------------------
__global__ __launch_bounds__(256) void k_soft(
    const float* __restrict__ part, const float* __restrict__ u_g,
    float* __restrict__ r_o, float* __restrict__ S2, float* __restrict__ S3,
    float* __restrict__ muu_g)
{
    int b = blockIdx.x, tid = threadIdx.x;
    int lane = tid & 63, wv = tid >> 6;
    __shared__ float red[16];
    __shared__ float stat[2];   // muu, varu

    float su = 0.f, suu = 0.f;
    for (int d = tid; d < DTCF; d += 256) {
        float x = u_g[b * DTCF + d];
        su += x; suu += x * x;
    }
    for (int off = 32; off > 0; off >>= 1) {
        su  += __shfl_xor(su, off);
        suu += __shfl_xor(suu, off);
    }
    if (lane == 0) { red[wv] = su; red[8 + wv] = suu; }
    __syncthreads();
    if (tid == 0) {
        float s  = red[0] + red[1] + red[2] + red[3];
        float ss = red[8] + red[9] + red[10] + red[11];
        float m = s * (1.f / DTCF);
        stat[0] = m;
        stat[1] = ss * (1.f / DTCF) - m * m;
        muu_g[b] = m;
    }
    __syncthreads();
    float mu = stat[0], vu = stat[1];

    int t0 = tid * 4;
    float4 sx = {0,0,0,0}, sxx = {0,0,0,0}, sxu = {0,0,0,0}, sxq = {0,0,0,0};
    #pragma unroll
    for (int dc = 0; dc < DC; ++dc) {
        const float* p = part + (((size_t)b * DC + dc) * 4) * TT + t0;
        float4 a = *(const float4*)(p);
        float4 bq = *(const float4*)(p + TT);
        float4 c = *(const float4*)(p + 2 * TT);
        float4 dq = *(const float4*)(p + 3 * TT);
        sx.x += a.x; sx.y += a.y; sx.z += a.z; sx.w += a.w;
        sxx.x += bq.x; sxx.y += bq.y; sxx.z += bq.z; sxx.w += bq.w;
        sxu.x += c.x; sxu.y += c.y; sxu.z += c.z; sxu.w += c.w;
        sxq.x += dq.x; sxq.y += dq.y; sxq.z += dq.z; sxq.w += dq.w;
    }
    const float inv_d = 1.f / DTCF, scale = 0.17677669529663687f;
    float mx[4], vx[4], cv[4], sc[4];
    float sxa[4]  = {sx.x, sx.y, sx.z, sx.w};
    float sxxa[4] = {sxx.x, sxx.y, sxx.z, sxx.w};
    float sxua[4] = {sxu.x, sxu.y, sxu.z, sxu.w};
    float sxqa[4] = {sxq.x, sxq.y, sxq.z, sxq.w};
    #pragma unroll
    for (int i = 0; i < 4; ++i) {
        mx[i] = sxa[i] * inv_d;
        vx[i] = sxxa[i] * inv_d - mx[i] * mx[i];
        cv[i] = sxua[i] * inv_d - mx[i] * mu;
        sc[i] = sxqa[i] * scale;
    }

    float m = fmaxf(fmaxf(sc[0], sc[1]), fmaxf(sc[2], sc[3]));
    for (int off = 32; off > 0; off >>= 1) m = fmaxf(m, __shfl_xor(m, off));
    if (lane == 0) red[wv] = m;
    __syncthreads();
    m = fmaxf(fmaxf(red[0], red[1]), fmaxf(red[2], red[3]));

    float e[4], sum = 0.f;
    #pragma unroll
    for (int i = 0; i < 4; ++i) { e[i] = __expf(sc[i] - m); sum += e[i]; }
    for (int off = 32; off > 0; off >>= 1) sum += __shfl_xor(sum, off);
    if (lane == 0) red[4 + wv] = sum;
    __syncthreads();
    sum = red[4] + red[5] + red[6] + red[7];
    float inv = 1.f / sum;

    float rr4[4], s2a = 0.f, s3a = 0.f;
    #pragma unroll
    for (int i = 0; i < 4; ++i) {
        float w = e[i] * inv;
        float vr = vx[i] + 2.f * w * cv[i] + w * w * vu;
        float rr = rsqrtf(vr + LNEPS);
        rr4[i] = rr;
        s2a += rr * w;
        s3a += rr * mx[i];
    }
    *(float4*)(r_o + (size_t)b * TT + t0) = make_float4(rr4[0], rr4[1], rr4[2], rr4[3]);

    for (int off = 32; off > 0; off >>= 1) {
        s2a += __shfl_xor(s2a, off);
        s3a += __shfl_xor(s3a, off);
    }
    if (lane == 0) { red[8 + wv] = s2a; red[12 + wv] = s3a; }
    __syncthreads();
    if (tid == 0) {
        S2[b] = (red[8] + red[9] + red[10] + red[11]) * (1.f / TT);
        S3[b] = (red[12] + red[13] + red[14] + red[15]) * (1.f / TT);
    }
}

// ---------------------------------------------------------------------------
// Kernel 3: pass B. One wave per (b,d) row: dot(r[b,:], tcf[b,d,:]).
// Reverse-b mapping to exploit L3 residue of pass A's stream. No fences.
// ---------------------------------------------------------------------------
__global__ __launch_bounds__(256) void k_passB(
    const float* __restrict__ tcf, const float* __restrict__ r,
    const float* __restrict__ u_g, const float* __restrict__ muu_g,
    const float* __restrict__ S2, const float* __restrict__ S3,
    const float* __restrict__ g1, const float* __restrict__ be1,
    float* __restrict__ pooled)
{
    int b = BN - 1 - blockIdx.x, dblk = blockIdx.y;
    int tid = threadIdx.x, wv = tid >> 6, lane = tid & 63;
    int d = dblk * 4 + wv;

    const float* row = tcf + ((size_t)b * DTCF + d) * TT;
    const float* rb  = r + (size_t)b * TT;

    float acc = 0.f;
    #pragma unroll
    for (int i = 0; i < 4; ++i) {
        float4 x  = *(const float4*)(row + i * 256 + lane * 4);
        float4 rv = *(const float4*)(rb + i * 256 + lane * 4);
        acc += rv.x * x.x + rv.y * x.y + rv.z * x.z + rv.w * x.w;
    }
    for (int off = 32; off > 0; off >>= 1) acc += __shfl_down(acc, off);

    if (lane == 0) {
        float pd = acc * (1.f / TT) - S3[b] + (u_g[b * DTCF + d] - muu_g[b]) * S2[b];
        pooled[b * DTCF + d] = g1[d] * pd + be1[d];
    }
}

// ---------------------------------------------------------------------------
// Kernel 4: head. One block per b; wave wv computes 16 hidden units via
// coalesced W1-row dots (no transpose needed); wave 0 does LN2+ELU+classes.
// ---------------------------------------------------------------------------
__global__ __launch_bounds__(256) void k_head(
    const float* __restrict__ pooled, const float* __restrict__ W1,
    const float* __restrict__ b1, const float* __restrict__ g2,
    const float* __restrict__ be2, const float* __restrict__ W2,
    const float* __restrict__ b2o, float* __restrict__ out)
{
    int b = blockIdx.x, tid = threadIdx.x;
    int lane = tid & 63, wv = tid >> 6;
    __shared__ float p_s[DTCF];
    __shared__ float h_s[HID];
    for (int i = tid; i < DTCF; i += 256) p_s[i] = pooled[b * DTCF + i];
    __syncthreads();

    #pragma unroll 4
    for (int jj = 0; jj < 16; ++jj) {
        int j = wv * 16 + jj;
        float a = 0.f;
        #pragma unroll
        for (int i = 0; i < 8; ++i)
            a += p_s[i * 64 + lane] * W1[j * DTCF + i * 64 + lane];
        for (int off = 32; off > 0; off >>= 1) a += __shfl_down(a, off);
        if (lane == 0) h_s[j] = a + b1[j];
    }
    __syncthreads();

    if (wv == 0) {
        int j = lane;
        float h = h_s[j];
        float mu = h;
        for (int off = 32; off > 0; off >>= 1) mu += __shfl_xor(mu, off);
        mu *= (1.f / HID);
        float df = h - mu;
        float vr = df * df;
        for (int off = 32; off > 0; off >>= 1) vr += __shfl_xor(vr, off);
        vr *= (1.f / HID);
        float hn = df * rsqrtf(vr + LNEPS) * g2[j] + be2[j];
        float he = hn > 0.f ? hn : expm1f(hn);
        #pragma unroll
        for (int c = 0; c < NCLS; ++c) {
            float v = he * W2[c * HID + j];
            for (int off = 32; off > 0; off >>= 1) v += __shfl_xor(v, off);
            if (j == 0) out[b * NCLS + c] = v + b2o[c];
        }
    }
}

extern "C" void kernel_launch(void* const* d_in, const int* in_sizes, int n_in,
                              void* d_out, int out_size, void* d_ws, size_t ws_size,
                              hipStream_t stream)
{
    const float* tcf  = (const float*)d_in[0];
    const float* gaf  = (const float*)d_in[1];
    const float* Wq   = (const float*)d_in[2];
    const float* Wkv  = (const float*)d_in[3];
    const float* Wout = (const float*)d_in[4];
    const float* ln1g = (const float*)d_in[5];
    const float* ln1b = (const float*)d_in[6];
    const float* W1   = (const float*)d_in[7];
    const float* b1   = (const float*)d_in[8];
    const float* ln2g = (const float*)d_in[9];
    const float* ln2b = (const float*)d_in[10];
    const float* W2   = (const float*)d_in[11];
    const float* b2   = (const float*)d_in[12];

    float* ws     = (float*)d_ws;
    float* u      = ws;                   // B*DTCF
    float* muu    = u + BN * DTCF;        // B
    float* r      = muu + BN;             // B*T
    float* S2     = r + BN * TT;          // B
    float* S3     = S2 + BN;              // B
    float* pooled = S3 + BN;              // B*DTCF
    float* part   = pooled + BN * DTCF;   // B*DC*4*T

    k_passA<<<dim3(BN, DC), 256, 0, stream>>>(tcf, gaf, Wq, Wkv, Wout, u, part);
    k_soft<<<BN, 256, 0, stream>>>(part, u, r, S2, S3, muu);
    k_passB<<<dim3(BN, DTCF / 4), 256, 0, stream>>>(
        tcf, r, u, muu, S2, S3, ln1g, ln1b, pooled);
    k_head<<<BN, 256, 0, stream>>>(pooled, W1, b1, ln2g, ln2b, W2, b2, (float*)d_out);
}